// Round 8
// baseline (94.014 us; speedup 1.0000x reference)
//
#include <hip/hip_runtime.h>

typedef __attribute__((ext_vector_type(8)))  short   short8;
typedef __attribute__((ext_vector_type(4)))  unsigned uint4v;
typedef __attribute__((ext_vector_type(16))) float   f32x16;
typedef __attribute__((ext_vector_type(4)))  float   f4;

constexpr int GRAM_BLOCKS = 256;
constexpr int MSE_BLOCKS  = 256;
constexpr int NB          = GRAM_BLOCKS + MSE_BLOCKS;   // 512 = all co-resident
constexpr int BLOCK       = 512;          // 8 waves; 2 blocks/CU -> 16 waves/CU
constexpr int CHUNK_F     = 3072;         // 16 slabs x 192 floats = 12 KiB
constexpr int CPW         = 8;            // 256 blocks * 8 waves * 8 = 16384 chunks
constexpr int RED_BLOCKS  = 96;
constexpr int MSE_THREADS = MSE_BLOCKS * BLOCK;  // 131072 -> exactly 16 f4 iters

// ws float-offsets:
//   [0..256)     MSE per-block partials (plain stores)
//   [256..768)   512 flag1 (every block sets flag1[bid]=1 w/ release)
//   [768..864)   96 flag2 (reducers); block0 resets all flags each call
//   [1024..4096) gram_final (3072)
//   [4608..4608+256*3072) per-block gram partial tiles (plain stores)
constexpr int MSE_OFF  = 0;
constexpr int F1_OFF   = 256;
constexpr int F2_OFF   = 768;
constexpr int GF_OFF   = 1024;
constexpr int PART_OFF = 4608;

struct F3 { float v[3]; };                 // 12B -> global_load_dwordx3
struct Chunk { F3 a0[4], a1[4], b0[4], b1[4]; };

// pack two f32 -> one u32 of 2 bf16 (round-half-up): 2 add + 1 v_perm
__device__ __forceinline__ unsigned pk_bf16(float a, float b) {
  unsigned a2 = __builtin_bit_cast(unsigned, a) + 0x8000u;
  unsigned b2 = __builtin_bit_cast(unsigned, b) + 0x8000u;
  return __builtin_amdgcn_perm(b2, a2, 0x07060302u);
}

__device__ __forceinline__ void load_chunk(const float* __restrict__ W, int c,
                                           int laneoff, Chunk& ch) {
  const float* s = W + (size_t)c * CHUNK_F + laneoff;
#pragma unroll
  for (int bp = 0; bp < 4; ++bp) {
    const float* p = s + bp * 384;     // slab pair (2bp, 2bp+1) of this half
    ch.a0[bp] = *(const F3*)(p);       // slab even, row r
    ch.a1[bp] = *(const F3*)(p + 96);  // slab even, row r+32
    ch.b0[bp] = *(const F3*)(p + 192); // slab odd,  row r
    ch.b1[bp] = *(const F3*)(p + 288); // slab odd,  row r+32
  }
}

__device__ __forceinline__ void mac_chunk(const Chunk& c, f32x16& a00, f32x16& a01,
                                          f32x16& a11) {
#pragma unroll
  for (int k = 0; k < 3; ++k) {
    unsigned fl[4], fh[4];
#pragma unroll
    for (int bp = 0; bp < 4; ++bp) {
      fl[bp] = pk_bf16(c.a0[bp].v[k], c.b0[bp].v[k]);
      fh[bp] = pk_bf16(c.a1[bp].v[k], c.b1[bp].v[k]);
    }
    uint4v vl = {fl[0], fl[1], fl[2], fl[3]};
    uint4v vh = {fh[0], fh[1], fh[2], fh[3]};
    short8 lo = __builtin_bit_cast(short8, vl);
    short8 hv = __builtin_bit_cast(short8, vh);
    a00 = __builtin_amdgcn_mfma_f32_32x32x16_bf16(lo, lo, a00, 0, 0, 0);
    a01 = __builtin_amdgcn_mfma_f32_32x32x16_bf16(lo, hv, a01, 0, 0, 0);
    a11 = __builtin_amdgcn_mfma_f32_32x32x16_bf16(hv, hv, a11, 0, 0, 0);
  }
}

__global__ __launch_bounds__(BLOCK, 4) void k_all(
    const float* __restrict__ X, const float* __restrict__ Y,
    const float* __restrict__ W, float* __restrict__ ws,
    float* __restrict__ out) {
  __shared__ __align__(16) float red[4][3072];   // 48 KiB
  __shared__ float r2[8][32];
  __shared__ float n2[64];
  __shared__ float fsum[8];
  __shared__ float wsum[8];
  const int bid  = blockIdx.x;
  const int tid  = threadIdx.x;
  const int wave = tid >> 6;
  const int lane = tid & 63;
  int* flag1 = (int*)(ws + F1_OFF);
  int* flag2 = (int*)(ws + F2_OFF);

  if (bid >= GRAM_BLOCKS) {
    // ---------------- MSE partial (nontemporal; plain per-block store) ----------
    const unsigned t0 = (unsigned)((bid - GRAM_BLOCKS) * BLOCK + tid);
    const f4* x4 = (const f4*)X;
    const f4* y4 = (const f4*)Y;
    float acc = 0.f;
#pragma unroll 8
    for (int it = 0; it < 16; ++it) {
      unsigned i = t0 + (unsigned)it * (unsigned)MSE_THREADS;
      f4 a = __builtin_nontemporal_load(x4 + i);
      f4 b = __builtin_nontemporal_load(y4 + i);
      float d0 = a[0] - b[0], d1 = a[1] - b[1], d2 = a[2] - b[2], d3 = a[3] - b[3];
      acc += d0 * d0 + d1 * d1 + d2 * d2 + d3 * d3;
    }
#pragma unroll
    for (int o = 32; o; o >>= 1) acc += __shfl_xor(acc, o, 64);
    if (lane == 0) fsum[wave] = acc;
    __syncthreads();
    if (tid == 0) {
      float m = 0.f;
#pragma unroll
      for (int wv = 0; wv < 8; ++wv) m += fsum[wv];
      ws[MSE_OFF + bid - GRAM_BLOCKS] = m;
      __threadfence();
      __hip_atomic_store(&flag1[bid], 1, __ATOMIC_RELEASE, __HIP_MEMORY_SCOPE_AGENT);
    }
    return;
  }

  // ------------- Gram partial: static 8 chunks/wave, reg double-buffer ----------
  const int r    = lane & 31;
  const int hi   = lane >> 5;
  const int laneoff = hi * 1536 + 3 * r;   // (hi*8 slabs)*192 + row r
  const int c0 = (bid * 8 + wave) * CPW;

  f32x16 a00{}, a01{}, a11{};
  Chunk ca, cb;
  load_chunk(W, c0, laneoff, ca);
#pragma unroll
  for (int t = 0; t < CPW; t += 2) {
    load_chunk(W, c0 + t + 1, laneoff, cb);
    mac_chunk(ca, a00, a01, a11);
    if (t + 2 < CPW) load_chunk(W, c0 + t + 2, laneoff, ca);
    mac_chunk(cb, a00, a01, a11);
  }

  // -------- block reduce (waves 0-3 store, waves 4-7 add, combine, store) -------
  if (wave < 4) {
    float* dst = red[wave];
#pragma unroll
    for (int rg = 0; rg < 16; ++rg) {
      dst[       rg * 64 + lane] = a00[rg];
      dst[1024 + rg * 64 + lane] = a01[rg];
      dst[2048 + rg * 64 + lane] = a11[rg];
    }
  }
  __syncthreads();
  if (wave >= 4) {
    float* dst = red[wave - 4];
#pragma unroll
    for (int rg = 0; rg < 16; ++rg) {
      dst[       rg * 64 + lane] += a00[rg];
      dst[1024 + rg * 64 + lane] += a01[rg];
      dst[2048 + rg * 64 + lane] += a11[rg];
    }
  }
  __syncthreads();
  {
    const f4* r0 = (const f4*)&red[0][0];
    const f4* r1 = (const f4*)&red[1][0];
    const f4* r2v = (const f4*)&red[2][0];
    const f4* r3 = (const f4*)&red[3][0];
    f4* p4 = (f4*)(ws + PART_OFF + (size_t)bid * 3072);
    for (int q = tid; q < 768; q += BLOCK)
      p4[q] = (r0[q] + r1[q]) + (r2v[q] + r3[q]);
  }
  __syncthreads();   // drains partial-tile stores (vmcnt) before publishing
  if (tid == 0) {
    __threadfence();
    __hip_atomic_store(&flag1[bid], 1, __ATOMIC_RELEASE, __HIP_MEMORY_SCOPE_AGENT);
  }
  if (bid >= RED_BLOCKS) return;

  // ======== reducer phase (gram blocks 0..95): 32 gram cols each ========
  if (tid < GRAM_BLOCKS)
    while (__hip_atomic_load(&flag1[tid], __ATOMIC_RELAXED,
                             __HIP_MEMORY_SCOPE_AGENT) != 1)
      __builtin_amdgcn_s_sleep(8);
  __syncthreads();
  __threadfence();

  {
    const int el = lane & 31, ph = lane >> 5;
    const int w0 = bid * 32;
    const float* base = ws + PART_OFF + (size_t)(ph + 2 * wave) * 3072 + w0 + el;
    float acc = 0.f;
#pragma unroll
    for (int i = 0; i < 16; ++i) acc += base[(size_t)i * 49152];  // +16 tiles/step
    acc += __shfl_xor(acc, 32, 64);
    if (ph == 0) r2[wave][el] = acc;
    __syncthreads();
    if (tid < 32) {
      float s = 0.f;
#pragma unroll
      for (int wv = 0; wv < 8; ++wv) s += r2[wv][tid];
      ws[GF_OFF + w0 + tid] = s;
    }
  }
  __syncthreads();
  if (tid == 0) {
    __threadfence();
    __hip_atomic_store(&flag2[bid], 1, __ATOMIC_RELEASE, __HIP_MEMORY_SCOPE_AGENT);
  }
  if (bid != 0) return;

  // ======== block 0: wait MSE flags + reducer flags, then finalize ========
  if (tid < MSE_BLOCKS) {
    while (__hip_atomic_load(&flag1[GRAM_BLOCKS + tid], __ATOMIC_RELAXED,
                             __HIP_MEMORY_SCOPE_AGENT) != 1)
      __builtin_amdgcn_s_sleep(8);
  } else if (tid < MSE_BLOCKS + RED_BLOCKS) {
    while (__hip_atomic_load(&flag2[tid - MSE_BLOCKS], __ATOMIC_RELAXED,
                             __HIP_MEMORY_SCOPE_AGENT) != 1)
      __builtin_amdgcn_s_sleep(8);
  }
  __syncthreads();
  __threadfence();

  float* g = &red[0][0];                       // reuse LDS
  for (int e = tid; e < 3072; e += BLOCK) g[e] = ws[GF_OFF + e];

  float m = (tid < MSE_BLOCKS) ? ws[MSE_OFF + tid] : 0.f;
#pragma unroll
  for (int o = 32; o; o >>= 1) m += __shfl_xor(m, o, 64);
  if (lane == 0) fsum[wave] = m;

  // reset flags for the next replay (all writers/consumers provably done)
  flag1[tid] = 0;
  if (tid < RED_BLOCKS) flag2[tid] = 0;
  __syncthreads();

  // C/D layout of 32x32 mfma: col = lane&31, row = (reg&3) + 8*(reg>>2) + 4*(lane>>5)
  for (int e = tid; e < 3072; e += BLOCK) {
    int tl = e >> 10, rg = (e >> 6) & 15, l = e & 63;
    int il = (rg & 3) + 8 * (rg >> 2) + 4 * (l >> 5);
    int jl = l & 31;
    if (tl != 1 && il == jl) n2[il + (tl == 2 ? 32 : 0)] = g[e];
  }
  __syncthreads();

  float local = 0.f;
  for (int e = tid; e < 3072; e += BLOCK) {
    int tl = e >> 10, rg = (e >> 6) & 15, l = e & 63;
    int il = (rg & 3) + 8 * (rg >> 2) + 4 * (l >> 5);
    int jl = l & 31;
    int i, j; float wgt;
    if (tl == 0)      { i = il;      j = jl;      wgt = 1.f; }
    else if (tl == 1) { i = il;      j = jl + 32; wgt = 2.f; }  // symmetric quadrant
    else              { i = il + 32; j = jl + 32; wgt = 1.f; }
    if (i != j) {
      float sim = g[e] / sqrtf(n2[i] * n2[j]);
      if (sim > 0.2f && sim <= 1.0f) local += wgt * sim;
    }
  }
#pragma unroll
  for (int o = 32; o; o >>= 1) local += __shfl_xor(local, o, 64);
  if (lane == 0) wsum[wave] = local;
  __syncthreads();
  if (tid == 0) {
    float reg_sum = 0.f, mse_sum = 0.f;
#pragma unroll
    for (int wv = 0; wv < 8; ++wv) { reg_sum += wsum[wv]; mse_sum += fsum[wv]; }
    out[0] = mse_sum * (1.0f / 8388608.0f) + 0.0005f * reg_sum;
  }
}

extern "C" void kernel_launch(void* const* d_in, const int* in_sizes, int n_in,
                              void* d_out, int out_size, void* d_ws, size_t ws_size,
                              hipStream_t stream) {
  const float* X = (const float*)d_in[0];
  const float* Y = (const float*)d_in[1];
  const float* W = (const float*)d_in[2];
  k_all<<<NB, BLOCK, 0, stream>>>(X, Y, W, (float*)d_ws, (float*)d_out);
}